// Round 1
// baseline (114.130 us; speedup 1.0000x reference)
//
#include <hip/hip_runtime.h>

#define N 2048
#define ZD 64

typedef float f32x4 __attribute__((ext_vector_type(4)));

// Kernel 1: pT[col][i] for col in [0,128):
//   col <  64 : (z @ W1[:64])[i][col] + b1[col]   (b1 folded)
//   col >= 64 : (z @ W1[64:])[i][col-64]
// Stored transposed so kernel 2 reads contiguous i/j runs.
__global__ __launch_bounds__(256) void edge_proj(
    const float* __restrict__ z, const float* __restrict__ W1,
    const float* __restrict__ b1, float* __restrict__ pT)
{
    const int t = threadIdx.x;
    const int i = blockIdx.x * 64 + (t & 63);
    const int colg = t >> 6;                       // wave-uniform
    const int col0 = blockIdx.y * 32 + colg * 8;

    // z row -> registers (64 floats, float4 loads; block's 16KB tile is L1-resident)
    float zr[ZD];
    const f32x4* zrow = (const f32x4*)(z + i * ZD);
    #pragma unroll
    for (int q = 0; q < ZD / 4; ++q) {
        f32x4 v = zrow[q];
        zr[q * 4 + 0] = v[0]; zr[q * 4 + 1] = v[1];
        zr[q * 4 + 2] = v[2]; zr[q * 4 + 3] = v[3];
    }

    float acc[8];
    #pragma unroll
    for (int cc = 0; cc < 8; ++cc) {
        // col is wave-uniform: force SGPR so W1/b1 become scalar loads
        const int col = __builtin_amdgcn_readfirstlane(col0 + cc);
        const float* w1c = (col < 64) ? (W1 + col) : (W1 + 64 * 64 + (col - 64));
        float a = (col < 64) ? b1[col] : 0.0f;
        #pragma unroll
        for (int d = 0; d < ZD; ++d)
            a = fmaf(zr[d], w1c[d * 64], a);
        acc[cc] = a;
    }
    #pragma unroll
    for (int cc = 0; cc < 8; ++cc)
        pT[(col0 + cc) * N + i] = acc[cc];   // coalesced: lanes = consecutive i
}

// Kernel 2: block computes a 64(i) x 128(j) tile of out.
// Thread (tx,ty) computes 4 rows x 8 cols. VALU-bound inner loop:
// per k per output: v_add + v_max + v_fmac (3 insts).
__global__ __launch_bounds__(256) void edge_main(
    const float* __restrict__ pT, const float* __restrict__ W2,
    const float* __restrict__ b2, float* __restrict__ out)
{
    __shared__ float ash[64][64];    // piT tile: ash[k][i_local]
    __shared__ float bsh[64][128];   // pjT tile: bsh[k][j_local]
    __shared__ float w2s[64];

    const int t = threadIdx.x;
    const int i0 = blockIdx.y * 64;
    const int j0 = blockIdx.x * 128;

    {
        const int k = t >> 2, q = t & 3;
        const float* arow = pT + k * N + i0;
        const float* brow = pT + (64 + k) * N + j0;
        #pragma unroll
        for (int rep = 0; rep < 4; ++rep) {
            const int f = (q + rep * 4) * 4;
            *(f32x4*)&ash[k][f] = *(const f32x4*)(arow + f);
        }
        #pragma unroll
        for (int rep = 0; rep < 8; ++rep) {
            const int f = (q + rep * 4) * 4;
            *(f32x4*)&bsh[k][f] = *(const f32x4*)(brow + f);
        }
        if (t < 64) w2s[t] = W2[t];
    }
    __syncthreads();

    const int tx = t & 15, ty = t >> 4;
    float acc[4][8];
    #pragma unroll
    for (int r = 0; r < 4; ++r)
        #pragma unroll
        for (int c = 0; c < 8; ++c) acc[r][c] = 0.0f;

    #pragma unroll 8
    for (int k = 0; k < 64; ++k) {
        f32x4 av  = *(const f32x4*)&ash[k][ty * 4];       // broadcast over tx
        f32x4 bv0 = *(const f32x4*)&bsh[k][tx * 8];
        f32x4 bv1 = *(const f32x4*)&bsh[k][tx * 8 + 4];
        const float w = w2s[k];
        #pragma unroll
        for (int r = 0; r < 4; ++r) {
            #pragma unroll
            for (int c = 0; c < 4; ++c) {
                float s0 = av[r] + bv0[c];
                acc[r][c]     = fmaf(fmaxf(s0, 0.0f), w, acc[r][c]);
                float s1 = av[r] + bv1[c];
                acc[r][c + 4] = fmaf(fmaxf(s1, 0.0f), w, acc[r][c + 4]);
            }
        }
    }

    const float bb = b2[0];
    #pragma unroll
    for (int r = 0; r < 4; ++r) {
        f32x4 o0, o1;
        #pragma unroll
        for (int c = 0; c < 4; ++c) {
            float x0 = acc[r][c] + bb;
            float x1 = acc[r][c + 4] + bb;
            o0[c] = __builtin_amdgcn_rcpf(1.0f + __expf(-x0));  // sigmoid
            o1[c] = __builtin_amdgcn_rcpf(1.0f + __expf(-x1));
        }
        float* orow = out + (i0 + ty * 4 + r) * N + j0 + tx * 8;
        *(f32x4*)orow       = o0;    // coalesced across tx
        *(f32x4*)(orow + 4) = o1;
    }
}

extern "C" void kernel_launch(void* const* d_in, const int* in_sizes, int n_in,
                              void* d_out, int out_size, void* d_ws, size_t ws_size,
                              hipStream_t stream) {
    const float* z  = (const float*)d_in[0];
    const float* W1 = (const float*)d_in[1];
    const float* b1 = (const float*)d_in[2];
    const float* W2 = (const float*)d_in[3];
    const float* b2 = (const float*)d_in[4];
    float* out = (float*)d_out;
    float* pT  = (float*)d_ws;   // 128 * 2048 floats = 1 MB scratch

    edge_proj<<<dim3(N / 64, 4), 256, 0, stream>>>(z, W1, b1, pT);
    edge_main<<<dim3(N / 128, N / 64), 256, 0, stream>>>(pT, W2, b2, out);
}

// Round 2
// 110.103 us; speedup vs baseline: 1.0366x; 1.0366x over previous
//
#include <hip/hip_runtime.h>

#define N 2048
#define ZD 64

typedef float f32x4 __attribute__((ext_vector_type(4)));

// Kernel 1: pT[col][i] for col in [0,128):
//   col <  64 : P = (z @ W1[:64])[i][col] + b1[col]   (b1 folded)
//   col >= 64 : Q = (z @ W1[64:])[i][col-64]
// Also emits r_part[p][i] = sum over this wave's 8 cols of P_or_Q[i][col]*W2[col&63]
// at pT + 128*N + p*N, p = blockIdx.y*4 + colgroup (p<8 -> ri parts, p>=8 -> rj parts).
__global__ __launch_bounds__(256) void edge_proj(
    const float* __restrict__ z, const float* __restrict__ W1,
    const float* __restrict__ b1, const float* __restrict__ W2,
    float* __restrict__ pT)
{
    const int t = threadIdx.x;
    const int i = blockIdx.x * 64 + (t & 63);
    const int colg = t >> 6;                       // wave-uniform
    const int col0 = blockIdx.y * 32 + colg * 8;

    // z row -> registers (64 floats, float4 loads)
    float zr[ZD];
    const f32x4* zrow = (const f32x4*)(z + i * ZD);
    #pragma unroll
    for (int q = 0; q < ZD / 4; ++q) {
        f32x4 v = zrow[q];
        zr[q * 4 + 0] = v[0]; zr[q * 4 + 1] = v[1];
        zr[q * 4 + 2] = v[2]; zr[q * 4 + 3] = v[3];
    }

    float acc[8];
    #pragma unroll
    for (int cc = 0; cc < 8; ++cc) {
        // col is wave-uniform: force SGPR so W1/b1 become scalar loads
        const int col = __builtin_amdgcn_readfirstlane(col0 + cc);
        const float* w1c = (col < 64) ? (W1 + col) : (W1 + 64 * 64 + (col - 64));
        float a = (col < 64) ? b1[col] : 0.0f;
        #pragma unroll
        for (int d = 0; d < ZD; ++d)
            a = fmaf(zr[d], w1c[d * 64], a);
        acc[cc] = a;
    }
    #pragma unroll
    for (int cc = 0; cc < 8; ++cc)
        pT[(col0 + cc) * N + i] = acc[cc];   // coalesced: lanes = consecutive i

    // rank-1 partials: sum_{cc} acc[cc] * W2[(col0+cc) & 63]
    float part = 0.0f;
    #pragma unroll
    for (int cc = 0; cc < 8; ++cc) {
        const int col = __builtin_amdgcn_readfirstlane(col0 + cc);
        part = fmaf(acc[cc], W2[col & 63], part);
    }
    const int p = blockIdx.y * 4 + colg;
    pT[128 * N + p * N + i] = part;
}

// Kernel 2: block computes 64(i) x 128(j) tile.
// abs trick: sum_k relu(P+Q)*w2 = 0.5*(ri + rj + sum_k |P+Q|*w2)
// Inner body per (output,k): v_add_f32 + v_fma_f32 with free abs() modifier = 2 VALU.
__global__ __launch_bounds__(256) void edge_main(
    const float* __restrict__ pT, const float* __restrict__ b2,
    float* __restrict__ out)
{
    __shared__ float ash[64][64];    // P tile: ash[k][i_local]
    __shared__ float bsh[64][128];   // Q tile: bsh[k][j_local]
    __shared__ float w2s[64];
    __shared__ float ris[64];
    __shared__ float rjs[128];

    const int t = threadIdx.x;
    const int i0 = blockIdx.y * 64;
    const int j0 = blockIdx.x * 128;
    const float* rp = pT + 128 * N;

    {
        const int k = t >> 2, q = t & 3;
        const float* arow = pT + k * N + i0;
        const float* brow = pT + (64 + k) * N + j0;
        #pragma unroll
        for (int rep = 0; rep < 4; ++rep) {
            const int f = (q + rep * 4) * 4;
            *(f32x4*)&ash[k][f] = *(const f32x4*)(arow + f);
        }
        #pragma unroll
        for (int rep = 0; rep < 8; ++rep) {
            const int f = (q + rep * 4) * 4;
            *(f32x4*)&bsh[k][f] = *(const f32x4*)(brow + f);
        }
        if (t < 64) {
            float s = 0.0f;
            #pragma unroll
            for (int p = 0; p < 8; ++p) s += rp[p * N + i0 + t];
            ris[t] = s;
        } else if (t < 192) {
            float s = 0.0f;
            #pragma unroll
            for (int p = 8; p < 16; ++p) s += rp[p * N + j0 + (t - 64)];
            rjs[t - 64] = s;
        } else {
            w2s[t - 192] = pT[(t - 192) * N];  // dummy to balance? no — real w2 below
        }
    }
    // w2 staged by threads 192..255 (real values)
    if (t >= 192) {
        // W2 values were folded into rp already? No: we need raw W2 per k here.
        // Recover from nothing — instead load from pT region? W2 not in pT.
    }
    __syncthreads();

    // NOTE: w2s must hold W2[k]; loaded via b2-adjacent pointer is not possible.
    // (w2 staged below via parameter — see edge_main2.)
    (void)b2; (void)out; (void)w2s;
}

// Corrected main kernel (single definition actually launched):
__global__ __launch_bounds__(256) void edge_main2(
    const float* __restrict__ pT, const float* __restrict__ W2,
    const float* __restrict__ b2, float* __restrict__ out)
{
    __shared__ float ash[64][64];    // P tile: ash[k][i_local]
    __shared__ float bsh[64][128];   // Q tile: bsh[k][j_local]
    __shared__ float w2s[64];
    __shared__ float ris[64];
    __shared__ float rjs[128];

    const int t = threadIdx.x;
    const int i0 = blockIdx.y * 64;
    const int j0 = blockIdx.x * 128;
    const float* rp = pT + 128 * N;

    {
        const int k = t >> 2, q = t & 3;
        const float* arow = pT + k * N + i0;
        const float* brow = pT + (64 + k) * N + j0;
        #pragma unroll
        for (int rep = 0; rep < 4; ++rep) {
            const int f = (q + rep * 4) * 4;
            *(f32x4*)&ash[k][f] = *(const f32x4*)(arow + f);
        }
        #pragma unroll
        for (int rep = 0; rep < 8; ++rep) {
            const int f = (q + rep * 4) * 4;
            *(f32x4*)&bsh[k][f] = *(const f32x4*)(brow + f);
        }
        if (t < 64) {
            float s = 0.0f;
            #pragma unroll
            for (int p = 0; p < 8; ++p) s += rp[p * N + i0 + t];
            ris[t] = s;
        } else if (t < 192) {
            float s = 0.0f;
            #pragma unroll
            for (int p = 8; p < 16; ++p) s += rp[p * N + j0 + (t - 64)];
            rjs[t - 64] = s;
        } else {
            w2s[t - 192] = W2[t - 192];
        }
    }
    __syncthreads();

    // thread tile: rows i0 + ty*4 + [0,4), cols j0 + tx*4 + [0,4) and j0 + 64 + tx*4 + [0,4)
    const int tx = t & 15, ty = t >> 4;
    float acc[4][8];
    #pragma unroll
    for (int r = 0; r < 4; ++r)
        #pragma unroll
        for (int c = 0; c < 8; ++c) acc[r][c] = 0.0f;

    #pragma unroll 2
    for (int k4 = 0; k4 < 64; k4 += 4) {
        f32x4 wv = *(const f32x4*)&w2s[k4];
        #pragma unroll
        for (int kk = 0; kk < 4; ++kk) {
            const int k = k4 + kk;
            f32x4 av  = *(const f32x4*)&ash[k][ty * 4];        // 4 rows, broadcast over tx
            f32x4 bv0 = *(const f32x4*)&bsh[k][tx * 4];        // 16 lanes x 16B contiguous
            f32x4 bv1 = *(const f32x4*)&bsh[k][64 + tx * 4];
            const float w = wv[kk];
            #pragma unroll
            for (int r = 0; r < 4; ++r) {
                #pragma unroll
                for (int c = 0; c < 4; ++c) {
                    float t0 = av[r] + bv0[c];
                    acc[r][c]     = fmaf(fabsf(t0), w, acc[r][c]);   // abs = free modifier
                    float t1 = av[r] + bv1[c];
                    acc[r][c + 4] = fmaf(fabsf(t1), w, acc[r][c + 4]);
                }
            }
        }
    }

    // epilogue: x = -1.4427*logit = C*acc + C*ri + C*rj - 1.4427*b2;  y = 1/(1+2^x)
    const float C = -0.72134752f;                 // -1/(2*log2(e))... = -log2(e)/2
    const float base = -1.44269504f * b2[0];
    float riC[4], rjC[8];
    #pragma unroll
    for (int r = 0; r < 4; ++r) riC[r] = fmaf(ris[ty * 4 + r], C, base);
    #pragma unroll
    for (int c = 0; c < 4; ++c) {
        rjC[c]     = rjs[tx * 4 + c] * C;
        rjC[c + 4] = rjs[64 + tx * 4 + c] * C;
    }

    #pragma unroll
    for (int r = 0; r < 4; ++r) {
        f32x4 o0, o1;
        #pragma unroll
        for (int c = 0; c < 4; ++c) {
            float x0 = fmaf(acc[r][c],     C, riC[r] + rjC[c]);
            float x1 = fmaf(acc[r][c + 4], C, riC[r] + rjC[c + 4]);
            o0[c] = __builtin_amdgcn_rcpf(1.0f + __builtin_amdgcn_exp2f(x0));
            o1[c] = __builtin_amdgcn_rcpf(1.0f + __builtin_amdgcn_exp2f(x1));
        }
        float* orow = out + (i0 + ty * 4 + r) * N + j0 + tx * 4;
        *(f32x4*)orow        = o0;
        *(f32x4*)(orow + 64) = o1;
    }
}

extern "C" void kernel_launch(void* const* d_in, const int* in_sizes, int n_in,
                              void* d_out, int out_size, void* d_ws, size_t ws_size,
                              hipStream_t stream) {
    const float* z  = (const float*)d_in[0];
    const float* W1 = (const float*)d_in[1];
    const float* b1 = (const float*)d_in[2];
    const float* W2 = (const float*)d_in[3];
    const float* b2 = (const float*)d_in[4];
    float* out = (float*)d_out;
    float* pT  = (float*)d_ws;   // 128*N floats (P,Q transposed) + 16*N floats (rank-1 partials)

    edge_proj<<<dim3(N / 64, 4), 256, 0, stream>>>(z, W1, b1, W2, pT);
    edge_main2<<<dim3(N / 128, N / 64), 256, 0, stream>>>(pT, W2, b2, out);
}

// Round 6
// 110.017 us; speedup vs baseline: 1.0374x; 1.0008x over previous
//
#include <hip/hip_runtime.h>

#define N 2048
#define ZD 64

typedef float f32x4 __attribute__((ext_vector_type(4)));
typedef float f32x2 __attribute__((ext_vector_type(2)));

// ws layout (f32): pT[128][N] transposed planes (P cols 0..63 with b1 folded,
// Q cols 64..127), then rp[16][N] rank-1 partials (p<8 sum to ri, p>=8 to rj).
// ri = P_i . W2, rj = Q_j . W2 for the relu split:
//   sum_k relu(P+Q)*w2 = 0.5*(ri + rj + sum_k |P+Q|*w2)

__global__ __launch_bounds__(256) void edge_proj(
    const float* __restrict__ z, const float* __restrict__ W1,
    const float* __restrict__ b1, const float* __restrict__ W2,
    float* __restrict__ pT)
{
    const int t = threadIdx.x;
    const int i = blockIdx.x * 64 + (t & 63);
    const int colg = t >> 6;                       // wave-uniform
    const int col0 = blockIdx.y * 32 + colg * 8;

    float zr[ZD];
    const f32x4* zrow = (const f32x4*)(z + i * ZD);
    #pragma unroll
    for (int q = 0; q < ZD / 4; ++q) {
        f32x4 v = zrow[q];
        zr[q * 4 + 0] = v[0]; zr[q * 4 + 1] = v[1];
        zr[q * 4 + 2] = v[2]; zr[q * 4 + 3] = v[3];
    }

    float acc[8];
    #pragma unroll
    for (int cc = 0; cc < 8; ++cc) {
        const int col = __builtin_amdgcn_readfirstlane(col0 + cc);
        const float* w1c = (col < 64) ? (W1 + col) : (W1 + 64 * 64 + (col - 64));
        float a = (col < 64) ? b1[col] : 0.0f;
        #pragma unroll
        for (int d = 0; d < ZD; ++d)
            a = fmaf(zr[d], w1c[d * 64], a);
        acc[cc] = a;
    }
    #pragma unroll
    for (int cc = 0; cc < 8; ++cc)
        pT[(col0 + cc) * N + i] = acc[cc];   // coalesced: lanes = consecutive i

    // exact f32 rank-1 partials
    float part = 0.0f;
    #pragma unroll
    for (int cc = 0; cc < 8; ++cc) {
        const int col = __builtin_amdgcn_readfirstlane(col0 + cc);
        part = fmaf(acc[cc], W2[col & 63], part);
    }
    float* rp = pT + 128 * N;
    const int p = blockIdx.y * 4 + colg;
    rp[p * N + i] = part;
}

// Block computes 64(i) x 128(j) tile. f32 abs-trick inner loop; adds expressed
// as float2 so the compiler may emit v_pk_add_f32 (exact same IEEE adds).
// Per 2 (out,k): 1 pk_add + 2 v_fma_f32(abs modifier) -> 1.5..2.0 VALU/(out*k).
__global__ __launch_bounds__(256) void edge_main2(
    const float* __restrict__ pT, const float* __restrict__ W2,
    const float* __restrict__ b2, float* __restrict__ out)
{
    __shared__ float ash[64][64];    // P tile: ash[k][i_local]
    __shared__ float bsh[64][128];   // Q tile: bsh[k][j_local]
    __shared__ float w2s[64];
    __shared__ float ris[64];
    __shared__ float rjs[128];

    const int t = threadIdx.x;
    const int i0 = blockIdx.y * 64;
    const int j0 = blockIdx.x * 128;
    const float* rp = pT + 128 * N;

    {
        const int k = t >> 2, q = t & 3;
        const float* arow = pT + k * N + i0;
        const float* brow = pT + (64 + k) * N + j0;
        #pragma unroll
        for (int rep = 0; rep < 4; ++rep) {
            const int f = (q + rep * 4) * 4;
            *(f32x4*)&ash[k][f] = *(const f32x4*)(arow + f);
        }
        #pragma unroll
        for (int rep = 0; rep < 8; ++rep) {
            const int f = (q + rep * 4) * 4;
            *(f32x4*)&bsh[k][f] = *(const f32x4*)(brow + f);
        }
        if (t < 64) {
            float s = 0.0f;
            #pragma unroll
            for (int p = 0; p < 8; ++p) s += rp[p * N + i0 + t];
            ris[t] = s;
        } else if (t < 192) {
            float s = 0.0f;
            #pragma unroll
            for (int p = 8; p < 16; ++p) s += rp[p * N + j0 + (t - 64)];
            rjs[t - 64] = s;
        } else {
            w2s[t - 192] = W2[t - 192];
        }
    }
    __syncthreads();

    const int tx = t & 15, ty = t >> 4;
    float acc[4][8];
    #pragma unroll
    for (int r = 0; r < 4; ++r)
        #pragma unroll
        for (int c = 0; c < 8; ++c) acc[r][c] = 0.0f;

    #pragma unroll 2
    for (int k4 = 0; k4 < 64; k4 += 4) {
        f32x4 wv = *(const f32x4*)&w2s[k4];
        #pragma unroll
        for (int kk = 0; kk < 4; ++kk) {
            const int k = k4 + kk;
            f32x4 av  = *(const f32x4*)&ash[k][ty * 4];        // 4 rows, bcast over tx
            f32x4 bv0 = *(const f32x4*)&bsh[k][tx * 4];        // 16 lanes x 16B contiguous
            f32x4 bv1 = *(const f32x4*)&bsh[k][64 + tx * 4];
            const float w = wv[kk];
            #pragma unroll
            for (int r = 0; r < 4; ++r) {
                f32x2 ar = { av[r], av[r] };                   // splat for pk_add
                #pragma unroll
                for (int c2 = 0; c2 < 2; ++c2) {
                    f32x2 b01 = { bv0[c2 * 2], bv0[c2 * 2 + 1] };
                    f32x2 t01 = ar + b01;                      // v_pk_add_f32 (exact)
                    acc[r][c2 * 2]     = fmaf(fabsf(t01[0]), w, acc[r][c2 * 2]);
                    acc[r][c2 * 2 + 1] = fmaf(fabsf(t01[1]), w, acc[r][c2 * 2 + 1]);
                    f32x2 b23 = { bv1[c2 * 2], bv1[c2 * 2 + 1] };
                    f32x2 t23 = ar + b23;
                    acc[r][c2 * 2 + 4] = fmaf(fabsf(t23[0]), w, acc[r][c2 * 2 + 4]);
                    acc[r][c2 * 2 + 5] = fmaf(fabsf(t23[1]), w, acc[r][c2 * 2 + 5]);
                }
            }
        }
    }

    // logit = 0.5*(ri + rj + abssum) + b2; x = -log2(e)*logit; y = 1/(1+2^x)
    const float C = -0.72134752f;                 // -log2(e)/2
    const float base = -1.44269504f * b2[0];
    float riC[4], rjC[8];
    #pragma unroll
    for (int r = 0; r < 4; ++r) riC[r] = fmaf(ris[ty * 4 + r], C, base);
    #pragma unroll
    for (int c = 0; c < 4; ++c) {
        rjC[c]     = rjs[tx * 4 + c] * C;
        rjC[c + 4] = rjs[64 + tx * 4 + c] * C;
    }

    #pragma unroll
    for (int r = 0; r < 4; ++r) {
        f32x4 o0, o1;
        #pragma unroll
        for (int c = 0; c < 4; ++c) {
            float x0 = fmaf(acc[r][c],     C, riC[r] + rjC[c]);
            float x1 = fmaf(acc[r][c + 4], C, riC[r] + rjC[c + 4]);
            o0[c] = __builtin_amdgcn_rcpf(1.0f + __builtin_amdgcn_exp2f(x0));
            o1[c] = __builtin_amdgcn_rcpf(1.0f + __builtin_amdgcn_exp2f(x1));
        }
        float* orow = out + (i0 + ty * 4 + r) * N + j0 + tx * 4;
        *(f32x4*)orow        = o0;
        *(f32x4*)(orow + 64) = o1;
    }
}

extern "C" void kernel_launch(void* const* d_in, const int* in_sizes, int n_in,
                              void* d_out, int out_size, void* d_ws, size_t ws_size,
                              hipStream_t stream) {
    const float* z  = (const float*)d_in[0];
    const float* W1 = (const float*)d_in[1];
    const float* b1 = (const float*)d_in[2];
    const float* W2 = (const float*)d_in[3];
    const float* b2 = (const float*)d_in[4];
    float* out = (float*)d_out;
    float* pT  = (float*)d_ws;   // 128*N f32 planes + 16*N f32 rank-1 partials

    edge_proj<<<dim3(N / 64, 4), 256, 0, stream>>>(z, W1, b1, W2, pT);
    edge_main2<<<dim3(N / 128, N / 64), 256, 0, stream>>>(pT, W2, b2, out);
}